// Round 7
// baseline (9425.440 us; speedup 1.0000x reference)
//
#include <hip/hip_runtime.h>
#include <stdint.h>

// SoftNMS (gaussian, sigma=0.5, thr=0.001), N=4096, 2 classes.
// R7: BATCHED CERTIFIED SELECTION. R1-R6 proved the per-step cost (~2.2us) is
// an irreducible serial-chain floor -> amortize it: per round, sort the front
// window of the score-sorted pool and certify the longest prefix of pairwise
// non-overlapping candidates that strictly beat tailmax (exact upper bound on
// everything outside the window). Certified prefix = provably the next k
// winners in order (inter==0 <=> decay bitwise 1.0; scores only decrease).
// Decay applied winner-major/slot-minor: per-slot multiplication order ==
// reference order, bitwise identical. tailmax fused into decay write-back.
// Fallback (0 certified): tailmax key IS the global max -> take it.

#define NB 4096
#define T 256
#define SLOTS 16          // NB / T register slots per thread
#define WCAP 64           // candidate window size
#define THR 0.001f

typedef unsigned long long u64;
typedef uint32_t u32;

__device__ __forceinline__ u64 kmax(u64 a, u64 b) { return a > b ? a : b; }
__device__ __forceinline__ u64 kmin(u64 a, u64 b) { return a < b ? a : b; }

// LLVM gfx9 wave64 reduction; identity 0, non-negative ints (validated R3-R6).
__device__ __forceinline__ int wave_max_nonneg(int v) {
    v = max(v, __builtin_amdgcn_update_dpp(0, v, 0x111, 0xf, 0xf, false));
    v = max(v, __builtin_amdgcn_update_dpp(0, v, 0x112, 0xf, 0xf, false));
    v = max(v, __builtin_amdgcn_update_dpp(0, v, 0x114, 0xf, 0xf, false));
    v = max(v, __builtin_amdgcn_update_dpp(0, v, 0x118, 0xf, 0xf, false));
    v = max(v, __builtin_amdgcn_update_dpp(0, v, 0x142, 0xa, 0xf, false));
    v = max(v, __builtin_amdgcn_update_dpp(0, v, 0x143, 0xc, 0xf, false));
    return __builtin_amdgcn_readlane(v, 63);
}
__device__ __forceinline__ u64 wave_max_key(u64 k) {
    int hi = (int)(u32)(k >> 32);
    int hm = wave_max_nonneg(hi);
    int lo = (hi == hm) ? (int)(u32)k : 0;
    int lm = wave_max_nonneg(lo);
    return ((u64)(u32)hm << 32) | (u64)(u32)lm;
}

// exact intersection area, same op sequence as R1-R6 decay (bitwise-critical)
__device__ __forceinline__ float inter_area(float ax1, float ay1, float ax2, float ay2,
                                            float bx1, float by1, float bx2, float by2) {
    float ix1 = fmaxf(ax1, bx1), iy1 = fmaxf(ay1, by1);
    float ix2 = fminf(ax2, bx2), iy2 = fminf(ay2, by2);
    float iw = fmaxf(__fsub_rn(ix2, ix1), 0.0f);
    float ih = fmaxf(__fsub_rn(iy2, iy1), 0.0f);
    return __fmul_rn(iw, ih);
}

// 8x8 region bitmask over [0,1000)^2 (125px cells). Boxes intersect =>
// region rectangles intersect => masks AND != 0 (monotone index fn).
__device__ __forceinline__ u64 region_mask(float x1, float y1, float x2, float y2) {
    int rx1 = (int)(x1 * 0.008f); rx1 = rx1 < 0 ? 0 : (rx1 > 7 ? 7 : rx1);
    int rx2 = (int)(x2 * 0.008f); rx2 = rx2 < 0 ? 0 : (rx2 > 7 ? 7 : rx2);
    int ry1 = (int)(y1 * 0.008f); ry1 = ry1 < 0 ? 0 : (ry1 > 7 ? 7 : ry1);
    int ry2 = (int)(y2 * 0.008f); ry2 = ry2 < 0 ? 0 : (ry2 > 7 ? 7 : ry2);
    u64 row = (u64)((2u << rx2) - (1u << rx1));
    u64 m = 0;
    for (int r = ry1; r <= ry2; ++r) m |= row << (8 * r);
    return m;
}

// workspace layout
#define WS_KEY(ws, c)  ((u64*)((char*)(ws) + (size_t)(c) * 32768))
#define WS_BOX(ws, c)  ((float4*)((char*)(ws) + 65536 + (size_t)(c) * 65536))
#define WS_CNT(ws)     ((int*)((char*)(ws) + 196608))

__launch_bounds__(T, 1)
__global__ void softnms_class(const float* __restrict__ boxes,
                              const float* __restrict__ scores,
                              const int* __restrict__ labels,
                              void* __restrict__ ws) {
    const int cls  = blockIdx.x;
    const int tid  = threadIdx.x;
    const int lane = tid & 63;
    const int wid  = tid >> 6;

    __shared__ u64    skey[NB];       // 32 KB: current keys, sorted-desc positions
    __shared__ u64    wkey[WCAP];     // round winner list
    __shared__ float4 wboxs[WCAP];
    __shared__ float  wareas[WCAP];
    __shared__ u64    wmasks[WCAP];
    __shared__ u64    red[4];
    __shared__ int    ctrl[3];        // count, done, wend

    const float4* boxes4 = reinterpret_cast<const float4*>(boxes);
    u64*    okey = WS_KEY(ws, cls);
    float4* obox = WS_BOX(ws, cls);

    // ---- setup 1: keys by original index (dead/other-class = 0) ----
    for (int j = 0; j < SLOTS; ++j) {
        int g = tid + T * j;
        u64 k = 0;
        if (labels[g] == cls) {
            float s = scores[g];
            k = ((u64)__float_as_uint(s) << 32) | ((u64)(u32)(4095 - g) << 16);
        }
        skey[g] = k;
    }
    __syncthreads();

    // ---- setup 2: bitonic sort skey[0..NB) DESCENDING (zeros sink) ----
    for (int k = 2; k <= NB; k <<= 1) {
        for (int j = k >> 1; j >= 1; j >>= 1) {
            for (int t = tid; t < NB / 2; t += T) {
                int i  = ((t & ~(j - 1)) << 1) | (t & (j - 1));
                int ip = i | j;
                u64 a = skey[i], b = skey[ip];
                bool dirmax = ((i & k) == 0);        // max at low idx -> descending
                if (dirmax ? (a < b) : (a > b)) { skey[i] = b; skey[ip] = a; }
            }
            __syncthreads();
        }
    }

    // ---- setup 3: register slots (key/box/area/mask) + init tailmax (p>=64) ----
    u64   key[SLOTS], smask[SLOTS];
    float x1r[SLOTS], y1r[SLOTS], x2r[SLOTS], y2r[SLOTS], ar[SLOTS];
    u64 tl0 = 0;
    for (int j = 0; j < SLOTS; ++j) {
        int p = tid + T * j;
        u64 k = skey[p];
        key[j] = k; smask[j] = 0;
        x1r[j] = 0; y1r[j] = 0; x2r[j] = 0; y2r[j] = 0; ar[j] = 0;
        if (k != 0) {
            int g = 4095 - (int)((k >> 16) & 0xFFFF);
            float4 b = boxes4[g];
            x1r[j] = b.x; y1r[j] = b.y; x2r[j] = b.z; y2r[j] = b.w;
            ar[j]  = __fmul_rn(__fsub_rn(b.z, b.x), __fsub_rn(b.w, b.y));
            smask[j] = region_mask(b.x, b.y, b.z, b.w);
        }
        if (p >= WCAP) tl0 = kmax(tl0, k);
    }
    {
        u64 tw = wave_max_key(tl0);
        if (lane == 0) red[wid] = tw;
    }
    __syncthreads();
    u64 tailmax = kmax(kmax(red[0], red[1]), kmax(red[2], red[3]));

    // ---- round loop ----
    int mcnt = 0;
    int cursor = 0;                    // maintained by wave 0 (uniform there)
    for (int round = 0; round < NB; ++round) {
        if (wid == 0) {
            int count = 0, doneF = 0;
            // A: advance cursor to first alive position
            for (;;) {
                if (cursor >= NB) break;
                int sp = cursor + lane;
                u64 kk = (sp < NB) ? skey[sp] : 0;
                u64 bal = __ballot(kk != 0);
                if (bal) { cursor += (int)__builtin_ctzll(bal); break; }
                cursor += 64;
            }
            int wend = cursor + WCAP;
            // B: load window, in-wave bitonic sort by current key (descending)
            int wp = cursor + lane;
            u64 v = (wp < NB) ? skey[wp] : 0;
            #pragma unroll
            for (int k = 2; k <= 64; k <<= 1) {
                #pragma unroll
                for (int j = k >> 1; j >= 1; j >>= 1) {
                    u64 o = __shfl_xor(v, j, 64);
                    bool selmax = (((lane & j) == 0) == ((lane & k) == 0));
                    v = selmax ? kmax(v, o) : kmin(v, o);
                }
            }
            // gather my sorted candidate's box (global; 64KB array is L2-hot)
            float cx1 = 0, cy1 = 0, cx2 = 0, cy2 = 0;
            if (v != 0) {
                int g = 4095 - (int)((v >> 16) & 0xFFFF);
                float4 b = boxes4[g];
                cx1 = b.x; cy1 = b.y; cx2 = b.z; cy2 = b.w;
            }
            u64 top0 = __shfl(v, 0, 64);
            if (top0 == 0 && tailmax == 0) {
                doneF = 1;
            } else {
                // C: certify longest independent prefix beating tailmax
                bool meCert = false;
                for (int i = 0; i < WCAP; ++i) {
                    u64 ki = __shfl(v, i, 64);
                    if (ki == 0 || !(ki > tailmax)) break;
                    float bx1 = __shfl(cx1, i, 64);
                    float by1 = __shfl(cy1, i, 64);
                    float bx2 = __shfl(cx2, i, 64);
                    float by2 = __shfl(cy2, i, 64);
                    bool ov = meCert &&
                        (inter_area(cx1, cy1, cx2, cy2, bx1, by1, bx2, by2) > 0.0f);
                    if (__ballot(ov)) break;
                    if (lane == i) {
                        meCert = true;
                        wkey[count]   = ki;
                        wboxs[count]  = make_float4(cx1, cy1, cx2, cy2);
                        wareas[count] = __fmul_rn(__fsub_rn(cx2, cx1), __fsub_rn(cy2, cy1));
                        wmasks[count] = region_mask(cx1, cy1, cx2, cy2);
                        okey[mcnt + count] = ki;
                        obox[mcnt + count] = make_float4(cx1, cy1, cx2, cy2);
                    }
                    ++count;
                }
                if (count == 0) {
                    // top0 <= tailmax (or 0), tailmax != 0 -> tailmax IS global max
                    u64 wk = tailmax;
                    int g = 4095 - (int)((wk >> 16) & 0xFFFF);
                    float4 b = boxes4[g];
                    if (lane == 0) {
                        wkey[0]   = wk;
                        wboxs[0]  = b;
                        wareas[0] = __fmul_rn(__fsub_rn(b.z, b.x), __fsub_rn(b.w, b.y));
                        wmasks[0] = region_mask(b.x, b.y, b.z, b.w);
                        okey[mcnt] = wk;
                        obox[mcnt] = b;
                    }
                    count = 1;
                }
            }
            if (lane == 0) { ctrl[0] = count; ctrl[1] = doneF; ctrl[2] = wend; }
        }
        __syncthreads();
        int count = ctrl[0];
        int doneF = ctrl[1];
        int wend  = ctrl[2];
        if (doneF) break;
        mcnt += count;

        // E: decay pass, winner-major / slot-minor (per-slot order == reference)
        u64 aor = 0;
        #pragma unroll
        for (int j = 0; j < SLOTS; ++j) aor |= key[j];
        if (aor != 0) {
            for (int w = 0; w < count; ++w) {
                u64 wk = wkey[w];
                float4 wb = wboxs[w];
                float wa = wareas[w];
                u64 wm = wmasks[w];
                #pragma unroll
                for (int j = 0; j < SLOTS; ++j) {
                    u64 kj = key[j];
                    if (kj == 0) continue;
                    if (kj == wk) { key[j] = 0; continue; }
                    if ((wm & smask[j]) == 0) continue;
                    float inter = inter_area(wb.x, wb.y, wb.z, wb.w,
                                             x1r[j], y1r[j], x2r[j], y2r[j]);
                    if (inter > 0.0f) {
                        float sc    = __uint_as_float((u32)(kj >> 32));
                        float denom = __fadd_rn(__fsub_rn(__fadd_rn(wa, ar[j]), inter), 1e-8f);
                        float iou   = inter / denom;                // IEEE div
                        float t2    = __fmul_rn(iou, iou);
                        float decay = expf(__fmul_rn(-2.0f, t2));   // exp(-iou^2/0.5)
                        float ns    = __fmul_rn(sc, decay);
                        key[j] = (ns >= THR)
                                   ? (((u64)__float_as_uint(ns) << 32) | (kj & 0xFFFFFFFFull))
                                   : 0;
                    }
                }
            }
        }
        // write back + fused tailmax over positions beyond this round's window
        u64 tl = 0;
        #pragma unroll
        for (int j = 0; j < SLOTS; ++j) {
            int p = tid + T * j;
            skey[p] = key[j];
            if (p >= wend) tl = kmax(tl, key[j]);
        }
        u64 tw = wave_max_key(tl);
        if (lane == 0) red[wid] = tw;
        __syncthreads();
        tailmax = kmax(kmax(red[0], red[1]), kmax(red[2], red[3]));
    }

    if (tid == 0) WS_CNT(ws)[cls] = mcnt;
}

// merge the two strictly-descending key lists by rank; pad the tail
__global__ void softnms_merge(void* __restrict__ ws, float* __restrict__ out) {
    int k = blockIdx.x * blockDim.x + threadIdx.x;   // 0..4095
    const u64*    keyA = WS_KEY(ws, 0);
    const u64*    keyB = WS_KEY(ws, 1);
    const float4* boxA = WS_BOX(ws, 0);
    const float4* boxB = WS_BOX(ws, 1);
    const int mA = WS_CNT(ws)[0];
    const int mB = WS_CNT(ws)[1];

    float* ob = out;
    float* os = out + NB * 4;
    float* ol = out + NB * 5;

    if (k < mA) {
        u64 x = keyA[k];
        int lo = 0, hi = mB;
        while (lo < hi) { int mid = (lo + hi) >> 1; if (keyB[mid] > x) lo = mid + 1; else hi = mid; }
        int pos = k + lo;
        float4 b = boxA[k];
        ob[pos * 4 + 0] = b.x; ob[pos * 4 + 1] = b.y;
        ob[pos * 4 + 2] = b.z; ob[pos * 4 + 3] = b.w;
        os[pos] = __uint_as_float((u32)(x >> 32));
        ol[pos] = 0.0f;
    } else if (k < mA + mB) {
        int i = k - mA;
        u64 x = keyB[i];
        int lo = 0, hi = mA;
        while (lo < hi) { int mid = (lo + hi) >> 1; if (keyA[mid] > x) lo = mid + 1; else hi = mid; }
        int pos = i + lo;
        float4 b = boxB[i];
        ob[pos * 4 + 0] = b.x; ob[pos * 4 + 1] = b.y;
        ob[pos * 4 + 2] = b.z; ob[pos * 4 + 3] = b.w;
        os[pos] = __uint_as_float((u32)(x >> 32));
        ol[pos] = 1.0f;
    } else {
        ob[k * 4 + 0] = 0.0f; ob[k * 4 + 1] = 0.0f;
        ob[k * 4 + 2] = 0.0f; ob[k * 4 + 3] = 0.0f;
        os[k] = 0.0f;
        ol[k] = -1.0f;
    }
}

extern "C" void kernel_launch(void* const* d_in, const int* in_sizes, int n_in,
                              void* d_out, int out_size, void* d_ws, size_t ws_size,
                              hipStream_t stream) {
    const float* boxes  = (const float*)d_in[0];
    const float* scores = (const float*)d_in[1];
    const int*   labels = (const int*)d_in[2];
    float* out = (float*)d_out;
    (void)in_sizes; (void)n_in; (void)out_size; (void)ws_size;
    softnms_class<<<2, T, 0, stream>>>(boxes, scores, labels, d_ws);
    softnms_merge<<<NB / 256, 256, 0, stream>>>(d_ws, out);
}